// Round 8
// baseline (5468.449 us; speedup 1.0000x reference)
//
#include <hip/hip_runtime.h>
#include <stdint.h>

#define NBATCH 128
#define NNEUR  4096
#define TLAST  180                      // outputs depend only on steps 0..180
#define DECAY  0.6065306597126334f      // float(exp(-0.5))
#define SCOPE  __HIP_MEMORY_SCOPE_AGENT

// Zero the 256 pair-flags each call (ws is poisoned / stale across replays).
__global__ void lif_init(unsigned* flags) {
    flags[threadIdx.x * 32] = 0u;       // 128B-strided flag cells
}

// Persistent kernel, TWO blocks per batch, pairwise producer/consumer sync.
// Grid: 256 blocks x 1024 threads, 1 block/CU (all co-resident: 256 <= capacity).
// Block bid handles batch b = bid&127, column half g = bid>>7 (cols [g*2048,+2048),
// 2 cols/thread, float2). Partner = bid^128 -> same XCD (ids congruent mod 8), so
// ballot-word + flag exchange stays in the local L2.
// Per step: each block publishes its 32 spike words + bumps its flag (release);
// partner polls the flag (acquire, load-only, no RMW) before decoding.
// volts / rec / window sums live in registers for the entire run.
__global__ __launch_bounds__(1024, 1) void lif_pair(
    const float* __restrict__ ff, const float* __restrict__ W,
    const float* __restrict__ rec0, float* __restrict__ out,
    unsigned long long* __restrict__ bits,   // 2 x [128][64] u64 (parity-buffered)
    unsigned* __restrict__ flags)            // 256 flags, 128B stride
{
#pragma clang fp contract(off)          // match numpy's separate mul/add roundings
    __shared__ __align__(16) unsigned short slist[NNEUR];
    __shared__ int scnt;

    const int tid  = threadIdx.x;
    const int lane = tid & 63;
    const int wid  = tid >> 6;
    const int bid  = blockIdx.x;
    const int b    = bid & 127;                       // batch
    const int g    = bid >> 7;                        // column half
    const int n0   = (g << 11) + (tid << 1);          // lane's first col
    const unsigned laneb = (unsigned)n0 * 4u;         // byte offset within a W row

    unsigned* myflag   = flags + bid * 32;
    unsigned* partflag = flags + (bid ^ 128) * 32;

    const char*  Wb   = (const char*)W;
    const float* fptr = ff + (((size_t)b * 200) << 12) + n0;
    const size_t idx  = ((size_t)b << 12) + (size_t)n0;

    float2 v2 = make_float2(0.f, 0.f);                // volts (regs, whole run)
    float2 r2 = *(const float2*)(rec0 + idx);         // rec
    float2 ss = v2, sv = v2;                          // window sums

    for (int t = 0; t <= TLAST; ++t) {
        const float2 f2 = *(const float2*)fptr;       // independent: overlaps gather
        fptr += NNEUR;

        float accx = 0.f, accy = 0.f;
        if (t > 0) {
            // ---- wait for partner's step-(t-1) ballots (load-only poll) ----
            if (tid == 0) {
                while ((int)__hip_atomic_load(partflag, __ATOMIC_ACQUIRE, SCOPE) < t)
                    __builtin_amdgcn_s_sleep(2);
            }
            __syncthreads();

            // ---- decode batch's 64 spike words into LDS index list (wave 0) ----
            const unsigned long long* bsrc =
                bits + (((size_t)((t - 1) & 1)) << 13) + (b << 6);
            if (wid == 0) {
                unsigned long long m =
                    __hip_atomic_load(&bsrc[lane], __ATOMIC_RELAXED, SCOPE);
                const int c = __popcll(m);
                int x = c;
                #pragma unroll
                for (int o = 1; o < 64; o <<= 1) {
                    int y = __shfl_up(x, (unsigned)o);
                    if (lane >= o) x += y;
                }
                if (lane == 63) scnt = x;
                int widx = x - c;                               // exclusive prefix
                const int jb = ((lane >> 1) << 7) + (lane & 1); // word's col base
                while (m) {
                    const int u = __builtin_ctzll(m);
                    m &= m - 1;
                    slist[widx++] = (unsigned short)(jb + (u << 1));
                }
            }
            __syncthreads();                          // slist ready

            // ---- sparse gather, 8-deep double-buffered float2 pipeline ----
            const int cnt = scnt;
            auto load8 = [&](float2* R, int ii) {
                const uint4 pk = *(const uint4*)(slist + ii);
                unsigned q[4];
                q[0] = pk.x; q[1] = pk.y; q[2] = pk.z; q[3] = pk.w;
                #pragma unroll
                for (int k = 0; k < 4; ++k) {
                    const unsigned qq = __builtin_amdgcn_readfirstlane(q[k]);
                    R[2 * k]     = *(const float2*)(Wb + (((qq & 0xffffu) << 14) + laneb));
                    R[2 * k + 1] = *(const float2*)(Wb + (((qq >> 16)     << 14) + laneb));
                }
            };
            auto acc8 = [&](const float2* R) {
                #pragma unroll
                for (int k = 0; k < 8; ++k) { accx += R[k].x; accy += R[k].y; }
            };

            int i = 0;
            if (cnt >= 8) {
                float2 A[8], B[8];
                load8(A, 0); i = 8;
                while (i + 16 <= cnt) {
                    load8(B, i);     acc8(A);
                    load8(A, i + 8); acc8(B);
                    i += 16;
                }
                if (i + 8 <= cnt) { load8(B, i); acc8(A); acc8(B); i += 8; }
                else              { acc8(A); }
            }
            for (; i < cnt; ++i) {
                unsigned q = (unsigned)slist[i];
                q = __builtin_amdgcn_readfirstlane(q);
                const float2 wv = *(const float2*)(Wb + ((q << 14) + laneb));
                accx += wv.x; accy += wv.y;
            }
        }

        // ---- elementwise LIF update (exact numpy op order) ----
        r2.x = r2.x * DECAY + accx * 0.5f;
        r2.y = r2.y * DECAY + accy * 0.5f;

        v2.x = v2.x * DECAY + 0.5f * (f2.x + r2.x);
        v2.y = v2.y * DECAY + 0.5f * (f2.y + r2.y);

        const bool s0 = v2.x >= 1.0f, s1 = v2.y >= 1.0f;
        if (s0) v2.x = 0.f;
        if (s1) v2.y = 0.f;

        // ---- publish this block's 32 spike words, then bump flag ----
        const unsigned long long m0 = __ballot(s0), m1 = __ballot(s1);
        if (t < TLAST) {
            if (lane == 0) {
                unsigned long long* dst =
                    bits + (((size_t)(t & 1)) << 13) + (b << 6) + (g << 5) + (wid << 1);
                __hip_atomic_store(&dst[0], m0, __ATOMIC_RELAXED, SCOPE);
                __hip_atomic_store(&dst[1], m1, __ATOMIC_RELAXED, SCOPE);
            }
        }

        // ---- recording windows (sums in registers) ----
        if (t >= 80) {
            const float2 s2 = make_float2(s0 ? 1.f : 0.f, s1 ? 1.f : 0.f);
            const bool start = (t == 80) || (t == 101) || (t == 121) ||
                               (t == 141) || (t == 161);
            if (start) {
                ss = s2; sv = v2;
            } else {
                ss.x += s2.x; ss.y += s2.y;
                sv.x += v2.x; sv.y += v2.y;
            }
            if (t == 100 || t == 120 || t == 140 || t == 160 || t == 180) {
                const int k = (t - 100) / 20;
                const size_t oidx = (((size_t)b * 5 + (size_t)k) << 12) + n0;
                float* rates = out;
                float* vavg  = out + (size_t)NBATCH * 5 * NNEUR;
                float* srec  = out + (size_t)NBATCH * 5 * NNEUR * 2;
                *(float2*)(rates + oidx) = make_float2(ss.x / 20.f, ss.y / 20.f);
                *(float2*)(vavg  + oidx) = make_float2(sv.x / 20.f, sv.y / 20.f);
                *(float2*)(srec  + oidx) = s2;
            }
        }

        if (t < TLAST) {
            __syncthreads();            // drains all waves' word stores (vmcnt 0)
            if (tid == 0)
                __hip_atomic_store(myflag, (unsigned)(t + 1), __ATOMIC_RELEASE, SCOPE);
        }
    }
}

extern "C" void kernel_launch(void* const* d_in, const int* in_sizes, int n_in,
                              void* d_out, int out_size, void* d_ws, size_t ws_size,
                              hipStream_t stream) {
    const float* ff   = (const float*)d_in[0];   // [128][200][4096] f32
    const float* W    = (const float*)d_in[1];   // [4096][4096] f32 (Wab_T)
    const float* rec0 = (const float*)d_in[2];   // [128][4096] f32
    float* out = (float*)d_out;                  // rates | volts_avg | spikes_rec

    char* ws = (char*)d_ws;
    unsigned long long* bits = (unsigned long long*)ws;        // 2*8192 u64 = 128 KB
    unsigned* flags = (unsigned*)(ws + 2 * 8192 * sizeof(unsigned long long));

    lif_init<<<dim3(1), dim3(256), 0, stream>>>(flags);
    lif_pair<<<dim3(256), dim3(1024), 0, stream>>>(ff, W, rec0, out, bits, flags);
}

// Round 9
// 3498.561 us; speedup vs baseline: 1.5631x; 1.5631x over previous
//
#include <hip/hip_runtime.h>
#include <stdint.h>

#define NBATCH 128
#define NNEUR  4096
#define TLAST  180                      // outputs depend only on steps 0..180
#define DECAY  0.6065306597126334f      // float(exp(-0.5))

// Champion structure (R1): one kernel per step, 512 blocks = 128 batches x 4
// column tiles (1024 cols), 256 threads = 4 waves, 4 cols/lane (float4).
// This round adds ONLY: non-temporal ff loads + non-temporal output stores
// (keep W / state cache-resident; ff is stream-once data that should not
// pollute L2/L3), and hoists the ff load to overlap the gather.
__global__ __launch_bounds__(256) void lif_step(
    const float* __restrict__ ff, const float* __restrict__ W,
    const float* __restrict__ rec0, float* __restrict__ out,
    float* __restrict__ volts, float* __restrict__ rec,
    float* __restrict__ sum_s, float* __restrict__ sum_v,
    const unsigned long long* __restrict__ bits_old,
    unsigned long long* __restrict__ bits_new, int t)
{
#pragma clang fp contract(off)          // match numpy's separate mul/add roundings
    __shared__ unsigned short slist[NNEUR];
    __shared__ int scnt;

    const int tid  = threadIdx.x;
    const int lane = tid & 63;
    const int wid  = tid >> 6;
    const int bid  = blockIdx.x;
    const int b    = bid >> 2;                         // batch
    const int c0   = ((bid & 3) << 10) + (wid << 8);   // wave's 256-col tile base
    const int n0   = c0 + (lane << 2);                 // this lane's 4 columns

    // ---- non-temporal ff load (stream-once; do not pollute L2/L3) ----
    const float* fsrc = ff + (((size_t)b * 200 + (size_t)t) << 12) + n0;
    const unsigned long long fl0 =
        __builtin_nontemporal_load((const unsigned long long*)fsrc);
    const unsigned long long fl1 =
        __builtin_nontemporal_load(((const unsigned long long*)fsrc) + 1);
    float4 f4;
    ((unsigned long long*)&f4)[0] = fl0;
    ((unsigned long long*)&f4)[1] = fl1;

    float4 acc = make_float4(0.f, 0.f, 0.f, 0.f);

    if (t > 0) {
        // ---- decode this batch's spike bitmask into an LDS index list (wave 0) ----
        if (wid == 0) {
            unsigned long long m = bits_old[(b << 6) + lane];   // word `lane`
            int c = __popcll(m);
            int x = c;
            #pragma unroll
            for (int o = 1; o < 64; o <<= 1) {
                int y = __shfl_up(x, (unsigned)o);
                if (lane >= o) x += y;
            }
            if (lane == 63) scnt = x;
            int widx = x - c;                                   // exclusive prefix
            const int jb = ((lane >> 2) << 8) + (lane & 3);     // c0(word) + k
            while (m) {
                int u = __builtin_ctzll(m);
                m &= m - 1;
                slist[widx++] = (unsigned short)(jb + (u << 2));
            }
        }
        __syncthreads();

        // ---- sparse gather: hidden slice = sum of spiking rows of W ----
        const int cnt = scnt;
        const float* wbase = W + n0;
        #pragma unroll 4
        for (int i = 0; i < cnt; ++i) {
            const int j = slist[i];                             // uniform per wave
            const float4 wv = *(const float4*)(wbase + ((size_t)j << 12));
            acc.x += wv.x; acc.y += wv.y; acc.z += wv.z; acc.w += wv.w;
        }
    }

    // ---- elementwise LIF update (exact numpy op order, no contraction) ----
    const size_t idx = ((size_t)b << 12) + (size_t)n0;

    float4 r4 = (t == 0) ? *(const float4*)(rec0 + idx)
                         : *(const float4*)(rec + idx);
    r4.x = r4.x * DECAY + acc.x * 0.5f;
    r4.y = r4.y * DECAY + acc.y * 0.5f;
    r4.z = r4.z * DECAY + acc.z * 0.5f;
    r4.w = r4.w * DECAY + acc.w * 0.5f;

    float4 v4 = make_float4(0.f, 0.f, 0.f, 0.f);
    if (t > 0) v4 = *(const float4*)(volts + idx);
    v4.x = v4.x * DECAY + 0.5f * (f4.x + r4.x);
    v4.y = v4.y * DECAY + 0.5f * (f4.y + r4.y);
    v4.z = v4.z * DECAY + 0.5f * (f4.z + r4.z);
    v4.w = v4.w * DECAY + 0.5f * (f4.w + r4.w);

    const bool s0 = v4.x >= 1.0f, s1 = v4.y >= 1.0f, s2 = v4.z >= 1.0f, s3 = v4.w >= 1.0f;
    if (s0) v4.x = 0.f;
    if (s1) v4.y = 0.f;
    if (s2) v4.z = 0.f;
    if (s3) v4.w = 0.f;

    *(float4*)(volts + idx) = v4;
    *(float4*)(rec + idx)   = r4;

    // ---- new spike bitmask: raw ballots, 4 words per wave ----
    const unsigned long long b0 = __ballot(s0), b1 = __ballot(s1),
                             b2 = __ballot(s2), b3 = __ballot(s3);
    if (lane == 0) {
        unsigned long long* dst = bits_new + (b << 6) + (c0 >> 6);
        dst[0] = b0; dst[1] = b1; dst[2] = b2; dst[3] = b3;
    }

    // ---- recording windows: steps 80..100 -> k0, 101..120 -> k1, ... 161..180 -> k4 ----
    if (t >= 80) {
        const float4 s4 = make_float4(s0 ? 1.f : 0.f, s1 ? 1.f : 0.f,
                                      s2 ? 1.f : 0.f, s3 ? 1.f : 0.f);
        const bool start = (t == 80) || (t == 101) || (t == 121) || (t == 141) || (t == 161);
        float4 ss, sv;
        if (start) {
            ss = s4; sv = v4;
        } else {
            ss = *(const float4*)(sum_s + idx);
            sv = *(const float4*)(sum_v + idx);
            ss.x += s4.x; ss.y += s4.y; ss.z += s4.z; ss.w += s4.w;
            sv.x += v4.x; sv.y += v4.y; sv.z += v4.z; sv.w += v4.w;
        }
        *(float4*)(sum_s + idx) = ss;
        *(float4*)(sum_v + idx) = sv;

        if (t >= 100 && ((t - 100) % 20) == 0) {
            const int k = (t - 100) / 20;
            const size_t oidx = (((size_t)b * 5 + (size_t)k) << 12) + n0;
            float* rates = out;
            float* vavg  = out + (size_t)NBATCH * 5 * NNEUR;
            float* srec  = out + (size_t)NBATCH * 5 * NNEUR * 2;

            auto nt_store4 = [](float* p, float4 v) {
                __builtin_nontemporal_store(((unsigned long long*)&v)[0],
                                            (unsigned long long*)p);
                __builtin_nontemporal_store(((unsigned long long*)&v)[1],
                                            ((unsigned long long*)p) + 1);
            };
            nt_store4(rates + oidx, make_float4(ss.x / 20.f, ss.y / 20.f,
                                                ss.z / 20.f, ss.w / 20.f));
            nt_store4(vavg + oidx,  make_float4(sv.x / 20.f, sv.y / 20.f,
                                                sv.z / 20.f, sv.w / 20.f));
            nt_store4(srec + oidx,  s4);
        }
    }
}

extern "C" void kernel_launch(void* const* d_in, const int* in_sizes, int n_in,
                              void* d_out, int out_size, void* d_ws, size_t ws_size,
                              hipStream_t stream) {
    const float* ff   = (const float*)d_in[0];   // [128][200][4096] f32
    const float* W    = (const float*)d_in[1];   // [4096][4096] f32 (Wab_T)
    const float* rec0 = (const float*)d_in[2];   // [128][4096] f32
    float* out = (float*)d_out;                  // rates | volts_avg | spikes_rec

    char* ws = (char*)d_ws;
    const size_t STATE = (size_t)NBATCH * NNEUR * sizeof(float);   // 2 MB
    float* volts = (float*)(ws);
    float* rec   = (float*)(ws + STATE);
    float* sum_s = (float*)(ws + 2 * STATE);
    float* sum_v = (float*)(ws + 3 * STATE);
    unsigned long long* bits = (unsigned long long*)(ws + 4 * STATE);
    const int BWORDS = NBATCH * (NNEUR / 64);    // 8192 words per buffer

    for (int t = 0; t <= TLAST; ++t) {
        lif_step<<<dim3(512), dim3(256), 0, stream>>>(
            ff, W, rec0, out, volts, rec, sum_s, sum_v,
            bits + (size_t)(t & 1) * BWORDS,
            bits + (size_t)((t + 1) & 1) * BWORDS, t);
    }
}